// Round 4
// baseline (171.206 us; speedup 1.0000x reference)
//
#include <hip/hip_runtime.h>

constexpr int Lc = 16;
constexpr int Cc = 16;
constexpr int Hc = 128;
constexpr int Wc = 256;
constexpr float DECAYc = 0.1f;
constexpr int HWc = Hc * Wc;

// float -> bf16 bits, round-to-nearest-even (inputs are finite normals).
__device__ inline unsigned short f2bf(float f) {
    unsigned int u = __float_as_uint(f);
    u += 0x7fffu + ((u >> 16) & 1u);
    return (unsigned short)(u >> 16);
}
// packed uint (bf16 pair) -> 2 floats
__device__ inline float2 bf2f2(unsigned int u) {
    return make_float2(__uint_as_float(u << 16),
                       __uint_as_float(u & 0xffff0000u));
}

constexpr int topbit(unsigned m) { int r = 0; while (m >>= 1) ++r; return r; }

// ---------------------------------------------------------------------------
// Kernel 1: transpose+convert img (L,C,H,W) f32 -> imgTb (L,H,W,C) bf16.
// (unchanged)
// ---------------------------------------------------------------------------
__global__ __launch_bounds__(256) void transpose_cvt_bf16(
    const float* __restrict__ img, unsigned short* __restrict__ imgTb)
{
    const int tid = threadIdx.x;
    const int h2 = tid & 1;
    const int wq = tid >> 1;             // 0..127
    const int kf  = blockIdx.x >> 5;     // 0..15
    const int px0 = (blockIdx.x & 31) * 1024;
    const float* __restrict__ srcb = img + (size_t)kf * Cc * HWc + (size_t)(8 * h2) * HWc;
#pragma unroll
    for (int rr = 0; rr < 8; ++rr) {
        const int px = px0 + rr * 128 + wq;
        float v[8];
#pragma unroll
        for (int c = 0; c < 8; ++c) v[c] = srcb[c * HWc + px];
        uint4 o;
        o.x = (unsigned int)f2bf(v[0]) | ((unsigned int)f2bf(v[1]) << 16);
        o.y = (unsigned int)f2bf(v[2]) | ((unsigned int)f2bf(v[3]) << 16);
        o.z = (unsigned int)f2bf(v[4]) | ((unsigned int)f2bf(v[5]) << 16);
        o.w = (unsigned int)f2bf(v[6]) | ((unsigned int)f2bf(v[7]) << 16);
        *(uint4*)(imgTb + ((size_t)kf * HWc + px) * Cc + 8 * h2) = o;
    }
}

// ---------------------------------------------------------------------------
// Masked chunk: for t in [TLO,THI] with (MASK>>t)&1 and t>k: compute coords,
// then issue ALL gathers back-to-back (memory ILP), then consume.
// Quad layout: lane handles 4 channels -> one 8B uint2 gather per corner.
// Each wave-quarter has <=3 active t per half-range -> <=12 loads in flight
// (bounds the ld/offs/wts buffers so VGPR stays ~70, ~7 waves/SIMD).
// x-wrap folded into x0&255 / x1&255 (bit-exact, validated round 2).
// ---------------------------------------------------------------------------
template <unsigned MASK, int TLO, int THI>
__device__ __forceinline__ void do_chunk_m(
    int k, const unsigned short* __restrict__ bk, int q,
    const float* sx1, const float* sy1, float fxk, float fyk,
    const float* __restrict__ wtab, float4* acc)
{
    constexpr int NT = THI - TLO + 1;
    int   offs[NT][4];
    float wts [NT][4];
    uint2 ld  [NT][4];

    // 1) coordinates + folded weights
#pragma unroll
    for (int t = TLO; t <= THI; ++t) {
        if (!((MASK >> t) & 1u)) continue;
        if (t > k) {
            const int j = t - TLO;
            const float wkt = wtab[t * Lc + k];
            const float ix = (sx1[t] - fxk) * (Wc * 0.5f) - 0.5f;
            const float iy = (sy1[t] - fyk) * (Hc * 0.5f) - 0.5f;
            const float x0f = floorf(ix);
            const float y0f = floorf(iy);
            const float wx = ix - x0f;
            const float wy = iy - y0f;
            const int x0 = (int)x0f;
            const int y0 = (int)y0f;
            const int x0r = x0 & (Wc - 1);
            const int x1r = (x0 + 1) & (Wc - 1);
            const int y0c = min(max(y0, 0), Hc - 1);
            const int y1c = min(max(y0 + 1, 0), Hc - 1);
            const float wb = wkt * wy;
            const float wa = wkt - wb;
            const float omx = 1.0f - wx;
            wts[j][0] = wa * omx;   // a00
            wts[j][1] = wa * wx;    // a10
            wts[j][2] = wb * omx;   // a01
            wts[j][3] = wb * wx;    // a11
            offs[j][0] = y0c * Wc + x0r;
            offs[j][1] = y0c * Wc + x1r;
            offs[j][2] = y1c * Wc + x0r;
            offs[j][3] = y1c * Wc + x1r;
        }
    }
    // 2) issue all loads
#pragma unroll
    for (int t = TLO; t <= THI; ++t) {
        if (!((MASK >> t) & 1u)) continue;
        if (t > k) {
            const int j = t - TLO;
#pragma unroll
            for (int n = 0; n < 4; ++n)
                ld[j][n] = ((const uint2*)(bk + (size_t)offs[j][n] * Cc))[q];
        }
    }
    // 3) convert + accumulate
#pragma unroll
    for (int t = TLO; t <= THI; ++t) {
        if (!((MASK >> t) & 1u)) continue;
        if (t > k) {
            const int j = t - TLO;
#pragma unroll
            for (int n = 0; n < 4; ++n) {
                const float2 f01 = bf2f2(ld[j][n].x);
                const float2 f23 = bf2f2(ld[j][n].y);
                const float a = wts[j][n];
                acc[t].x += a * f01.x;
                acc[t].y += a * f01.y;
                acc[t].z += a * f23.x;
                acc[t].w += a * f23.y;
            }
        }
    }
}

// ---------------------------------------------------------------------------
// One t-quarter (MASK) for one pixel-quad lane. LOOPM strips t=0 (identity
// only). All instruction counts identical to the round-0 all-t kernel; the
// quarter just owns 1/4 of the t's.
// ---------------------------------------------------------------------------
template <unsigned MASK>
__device__ __forceinline__ void run_quarter(
    const unsigned short* __restrict__ imgTb,
    const float* __restrict__ cum_flow,
    const float* __restrict__ img,
    float* __restrict__ out,
    const float* wtab,
    int q, int pix, float base_x, float base_y)
{
    constexpr unsigned LOOPM = MASK & ~1u;   // t=0 never samples (k<t empty)

    float sx1[Lc], sy1[Lc];
#pragma unroll
    for (int t = 0; t < Lc; ++t) {
        if (!((LOOPM >> t) & 1u)) continue;
        sx1[t] = base_x + cum_flow[(t * 2 + 0) * HWc + pix] + 1.0f;
        sy1[t] = base_y + cum_flow[(t * 2 + 1) * HWc + pix] + 1.0f;
    }

    float4 acc[Lc];
#pragma unroll
    for (int t = 0; t < Lc; ++t)
        if ((MASK >> t) & 1u) acc[t] = make_float4(0.f, 0.f, 0.f, 0.f);

    constexpr int KMAX = topbit(MASK);   // highest masked t; k in [0, KMAX)
    for (int k = 0; k < KMAX; ++k) {
        const float fxk = cum_flow[(k * 2 + 0) * HWc + pix];
        const float fyk = cum_flow[(k * 2 + 1) * HWc + pix];
        const unsigned short* __restrict__ bk = imgTb + (size_t)k * HWc * Cc;
        do_chunk_m<LOOPM, 1, 7>(k, bk, q, sx1, sy1, fxk, fyk, wtab, acc);
        do_chunk_m<LOOPM, 8, 15>(k, bk, q, sx1, sy1, fxk, fyk, wtab, acc);
    }

    // Epilogue: add exact fp32 identity sample (t==k, weight 1) and store.
#pragma unroll
    for (int t = 0; t < Lc; ++t) {
        if (!((MASK >> t) & 1u)) continue;
        const float* __restrict__ ip = img + ((size_t)t * Cc + 4 * q) * HWc + pix;
        float* __restrict__ op = out + ((size_t)t * Cc + 4 * q) * HWc + pix;
        op[0 * HWc] = acc[t].x + ip[0 * HWc];
        op[1 * HWc] = acc[t].y + ip[1 * HWc];
        op[2 * HWc] = acc[t].z + ip[2 * HWc];
        op[3 * HWc] = acc[t].w + ip[3 * HWc];
    }
}

// ---------------------------------------------------------------------------
// Kernel 2: wave-level t-quartered quad-layout accumulate.
// Block = 16 px x 16 lanes (4 waves). Wave id (tid>>6) picks one of the
// equal-30-pair t-quarters {15,9,6} {14,12,4} {13,11,3,2,1} {10,8,7,5,0}.
//  - mask is wave-uniform -> no divergence; quarters write disjoint t-planes
//    -> no combine;
//  - all quarters of a pixel share the block -> frames swept in lockstep
//    (round 1/2 put quarters in different blocks and refetched frames, +70MB);
//  - within a wave: round-0 quad layout (q=tid&3 channel-quad, 16 px/wave)
//    -> 8B gathers, 64B store/identity segments (round 3's octant 32B
//    segments cost +20MB fetch AND write);
//  - total VALU + VMEM instruction count identical to round 0, but waves
//    2048 -> 8192 (2048 blocks = 8/CU, 32 waves/CU grid cap; VGPR ~70 ->
//    ~7/SIMD cap) -> 3-4x the latency hiding of round 0's 20% occupancy.
// band = b&7 -> XCD under modulo dispatch, same slicing as round 0.
// ---------------------------------------------------------------------------
__global__ __launch_bounds__(256, 6) void gridsample_bf16_wq(
    const unsigned short* __restrict__ imgTb,  // (L, H, W, C) bf16
    const float* __restrict__ cum_flow,        // (L, 2, H, W)
    const float* __restrict__ mask,            // (L, L)
    const float* __restrict__ decay,           // (L, L)
    const float* __restrict__ img,             // (L, C, H, W) f32, identity
    float* __restrict__ out)                   // (L, C, H, W)
{
    __shared__ float wtab[Lc * Lc];
    const int tid = threadIdx.x;
    if (tid < Lc * Lc)
        wtab[tid] = mask[tid] * __expf(-DECAYc * decay[tid]);
    __syncthreads();

    const int q    = tid & 3;            // channel quad 4q..4q+3
    const int px16 = (tid >> 2) & 15;    // pixel within block
    const int wv   = tid >> 6;           // wave id = t-quarter
    const int b    = blockIdx.x;         // 0..2047
    const int band = b & 7;              // XCD id under modulo dispatch
    const int sub  = b >> 3;             // 0..255 within band
    const int h = band * 16 + (sub >> 4);
    const int w = (sub & 15) * 16 + px16;
    const int pix = h * Wc + w;

    const float base_x = w * (2.0f / Wc) - 1.0f + 1.0f / Wc;
    const float base_y = h * (2.0f / Hc) - 1.0f + 1.0f / Hc;

    switch (wv) {
        case 0:  run_quarter<0x8240u>(imgTb, cum_flow, img, out, wtab, q, pix, base_x, base_y); break; // {15,9,6}
        case 1:  run_quarter<0x5010u>(imgTb, cum_flow, img, out, wtab, q, pix, base_x, base_y); break; // {14,12,4}
        case 2:  run_quarter<0x280Eu>(imgTb, cum_flow, img, out, wtab, q, pix, base_x, base_y); break; // {13,11,3,2,1}
        default: run_quarter<0x05A1u>(imgTb, cum_flow, img, out, wtab, q, pix, base_x, base_y); break; // {10,8,7,5,0}
    }
}

// ---------------------------------------------------------------------------
// Fallback (Round-1 kernel): used only if ws_size is too small.
// ---------------------------------------------------------------------------
__global__ __launch_bounds__(256) void gridsample_warp_acc(
    const float* __restrict__ img, const float* __restrict__ cum_flow,
    const float* __restrict__ mask, const float* __restrict__ decay,
    float* __restrict__ out)
{
    const int w = threadIdx.x, h = blockIdx.x, t = blockIdx.y;
    const int pix = h * Wc + w;
    const float base_x = w * (2.0f / Wc) - 1.0f + 1.0f / Wc;
    const float base_y = h * (2.0f / Hc) - 1.0f + 1.0f / Hc;
    const float fxt = cum_flow[(t * 2 + 0) * HWc + pix];
    const float fyt = cum_flow[(t * 2 + 1) * HWc + pix];
    float acc[Cc];
#pragma unroll
    for (int c = 0; c < Cc; ++c) acc[c] = 0.0f;
    for (int k = 0; k <= t; ++k) {
        const float wkt = mask[t * Lc + k] * __expf(-DECAYc * decay[t * Lc + k]);
        const float fxk = cum_flow[(k * 2 + 0) * HWc + pix];
        const float fyk = cum_flow[(k * 2 + 1) * HWc + pix];
        float gx = base_x + (fxt - fxk);
        const float gy = base_y + (fyt - fyk);
        float m = gx + 1.0f;
        m -= 2.0f * floorf(m * 0.5f);
        gx = m - 1.0f;
        const float ix = (gx + 1.0f) * (Wc * 0.5f) - 0.5f;
        const float iy = (gy + 1.0f) * (Hc * 0.5f) - 0.5f;
        const float x0f = floorf(ix), y0f = floorf(iy);
        const float wx = ix - x0f, wy = iy - y0f;
        const int x0 = (int)x0f, y0 = (int)y0f;
        const int x0r = x0 & (Wc - 1), x1r = (x0 + 1) & (Wc - 1);
        const int y0c = min(max(y0, 0), Hc - 1), y1c = min(max(y0 + 1, 0), Hc - 1);
        const float a00 = wkt * (1.0f - wx) * (1.0f - wy);
        const float a01 = wkt * (1.0f - wx) * wy;
        const float a10 = wkt * wx * (1.0f - wy);
        const float a11 = wkt * wx * wy;
        const int o00 = y0c * Wc + x0r, o01 = y1c * Wc + x0r;
        const int o10 = y0c * Wc + x1r, o11 = y1c * Wc + x1r;
        const float* __restrict__ ik = img + (size_t)k * Cc * HWc;
#pragma unroll
        for (int c = 0; c < Cc; ++c) {
            const float* __restrict__ p = ik + c * HWc;
            acc[c] += p[o00] * a00 + p[o01] * a01 + p[o10] * a10 + p[o11] * a11;
        }
    }
    float* __restrict__ op = out + (size_t)t * Cc * HWc + pix;
#pragma unroll
    for (int c = 0; c < Cc; ++c) op[c * HWc] = acc[c];
}

extern "C" void kernel_launch(void* const* d_in, const int* in_sizes, int n_in,
                              void* d_out, int out_size, void* d_ws, size_t ws_size,
                              hipStream_t stream) {
    const float* img      = (const float*)d_in[0];
    const float* cum_flow = (const float*)d_in[1];
    const float* mask     = (const float*)d_in[2];
    const float* decay    = (const float*)d_in[3];
    float* out = (float*)d_out;

    const size_t needed = (size_t)Lc * HWc * Cc * sizeof(unsigned short);  // 16 MB
    if (ws_size >= needed) {
        unsigned short* imgTb = (unsigned short*)d_ws;
        transpose_cvt_bf16<<<dim3(512), 256, 0, stream>>>(img, imgTb);
        gridsample_bf16_wq<<<dim3(2048), 256, 0, stream>>>(
            imgTb, cum_flow, mask, decay, img, out);
    } else {
        dim3 grid(Hc, Lc, 1);
        gridsample_warp_acc<<<grid, Wc, 0, stream>>>(img, cum_flow, mask, decay, out);
    }
}

// Round 5
// 162.589 us; speedup vs baseline: 1.0530x; 1.0530x over previous
//
#include <hip/hip_runtime.h>

constexpr int Lc = 16;
constexpr int Cc = 16;
constexpr int Hc = 128;
constexpr int Wc = 256;
constexpr float DECAYc = 0.1f;
constexpr int HWc = Hc * Wc;

// float -> bf16 bits, round-to-nearest-even (inputs are finite normals).
__device__ inline unsigned short f2bf(float f) {
    unsigned int u = __float_as_uint(f);
    u += 0x7fffu + ((u >> 16) & 1u);
    return (unsigned short)(u >> 16);
}
// packed uint (bf16 pair) -> 2 floats
__device__ inline float2 bf2f2(unsigned int u) {
    return make_float2(__uint_as_float(u << 16),
                       __uint_as_float(u & 0xffff0000u));
}

constexpr int topbit(unsigned m) { int r = 0; while (m >>= 1) ++r; return r; }

// ---------------------------------------------------------------------------
// Kernel 1: transpose+convert img (L,C,H,W) f32 -> imgTb (L,H,W,C) bf16.
// (unchanged)
// ---------------------------------------------------------------------------
__global__ __launch_bounds__(256) void transpose_cvt_bf16(
    const float* __restrict__ img, unsigned short* __restrict__ imgTb)
{
    const int tid = threadIdx.x;
    const int h2 = tid & 1;
    const int wq = tid >> 1;             // 0..127
    const int kf  = blockIdx.x >> 5;     // 0..15
    const int px0 = (blockIdx.x & 31) * 1024;
    const float* __restrict__ srcb = img + (size_t)kf * Cc * HWc + (size_t)(8 * h2) * HWc;
#pragma unroll
    for (int rr = 0; rr < 8; ++rr) {
        const int px = px0 + rr * 128 + wq;
        float v[8];
#pragma unroll
        for (int c = 0; c < 8; ++c) v[c] = srcb[c * HWc + px];
        uint4 o;
        o.x = (unsigned int)f2bf(v[0]) | ((unsigned int)f2bf(v[1]) << 16);
        o.y = (unsigned int)f2bf(v[2]) | ((unsigned int)f2bf(v[3]) << 16);
        o.z = (unsigned int)f2bf(v[4]) | ((unsigned int)f2bf(v[5]) << 16);
        o.w = (unsigned int)f2bf(v[6]) | ((unsigned int)f2bf(v[7]) << 16);
        *(uint4*)(imgTb + ((size_t)kf * HWc + px) * Cc + 8 * h2) = o;
    }
}

// ---------------------------------------------------------------------------
// Masked chunk, 16B-gather variant: for t in [TLO,THI] with (MASK>>t)&1 and
// t>k (wave-uniform): compute coords, issue ALL gathers back-to-back, then
// consume. Lane handles 8 channels -> one 16B uint4 gather per corner; the
// two half-lanes of a pixel cover its full 32B record (no wasted line
// bytes). Quarter masks are chosen so each 8-range holds <=2 active t ->
// <=8 uint4 loads in flight (32 VGPR), keeping total pressure <=128.
// x-wrap folded into x0&255 / x1&255 (bit-exact, validated round 2).
// ---------------------------------------------------------------------------
template <unsigned MASK, int TLO, int THI>
__device__ __forceinline__ void do_chunk16(
    int k, const unsigned short* __restrict__ bk, int half,
    const float* sx1, const float* sy1, float fxk, float fyk,
    const float* __restrict__ wtab, float (*acc)[8])
{
    constexpr int NT = THI - TLO + 1;
    int   offs[NT][4];
    float wts [NT][4];
    uint4 ld  [NT][4];

    // 1) coordinates + folded weights
#pragma unroll
    for (int t = TLO; t <= THI; ++t) {
        if (!((MASK >> t) & 1u)) continue;
        if (t > k) {
            const int j = t - TLO;
            const float wkt = wtab[t * Lc + k];
            const float ix = (sx1[t] - fxk) * (Wc * 0.5f) - 0.5f;
            const float iy = (sy1[t] - fyk) * (Hc * 0.5f) - 0.5f;
            const float x0f = floorf(ix);
            const float y0f = floorf(iy);
            const float wx = ix - x0f;
            const float wy = iy - y0f;
            const int x0 = (int)x0f;
            const int y0 = (int)y0f;
            const int x0r = x0 & (Wc - 1);
            const int x1r = (x0 + 1) & (Wc - 1);
            const int y0c = min(max(y0, 0), Hc - 1);
            const int y1c = min(max(y0 + 1, 0), Hc - 1);
            const float wb = wkt * wy;
            const float wa = wkt - wb;
            const float omx = 1.0f - wx;
            wts[j][0] = wa * omx;   // a00
            wts[j][1] = wa * wx;    // a10
            wts[j][2] = wb * omx;   // a01
            wts[j][3] = wb * wx;    // a11
            offs[j][0] = y0c * Wc + x0r;
            offs[j][1] = y0c * Wc + x1r;
            offs[j][2] = y1c * Wc + x0r;
            offs[j][3] = y1c * Wc + x1r;
        }
    }
    // 2) issue all loads (up to 8 uint4 in flight)
#pragma unroll
    for (int t = TLO; t <= THI; ++t) {
        if (!((MASK >> t) & 1u)) continue;
        if (t > k) {
            const int j = t - TLO;
#pragma unroll
            for (int n = 0; n < 4; ++n)
                ld[j][n] = ((const uint4*)(bk + (size_t)offs[j][n] * Cc))[half];
        }
    }
    // 3) convert + accumulate (8 channels per lane)
#pragma unroll
    for (int t = TLO; t <= THI; ++t) {
        if (!((MASK >> t) & 1u)) continue;
        if (t > k) {
            const int j = t - TLO;
#pragma unroll
            for (int n = 0; n < 4; ++n) {
                const float a = wts[j][n];
                const float2 f01 = bf2f2(ld[j][n].x);
                const float2 f23 = bf2f2(ld[j][n].y);
                const float2 f45 = bf2f2(ld[j][n].z);
                const float2 f67 = bf2f2(ld[j][n].w);
                acc[t][0] += a * f01.x;
                acc[t][1] += a * f01.y;
                acc[t][2] += a * f23.x;
                acc[t][3] += a * f23.y;
                acc[t][4] += a * f45.x;
                acc[t][5] += a * f45.y;
                acc[t][6] += a * f67.x;
                acc[t][7] += a * f67.y;
            }
        }
    }
}

// ---------------------------------------------------------------------------
// One t-quarter (MASK) for one (pixel, channel-half) lane.
// ---------------------------------------------------------------------------
template <unsigned MASK>
__device__ __forceinline__ void run_quarter(
    const unsigned short* __restrict__ imgTb,
    const float* __restrict__ cum_flow,
    const float* __restrict__ img,
    float* __restrict__ out,
    const float* wtab,
    int half, int pix, float base_x, float base_y)
{
    constexpr unsigned LOOPM = MASK & ~1u;   // t=0 never samples (k<t empty)

    float sx1[Lc], sy1[Lc];
#pragma unroll
    for (int t = 0; t < Lc; ++t) {
        if (!((LOOPM >> t) & 1u)) continue;
        sx1[t] = base_x + cum_flow[(t * 2 + 0) * HWc + pix] + 1.0f;
        sy1[t] = base_y + cum_flow[(t * 2 + 1) * HWc + pix] + 1.0f;
    }

    float acc[Lc][8];
#pragma unroll
    for (int t = 0; t < Lc; ++t) {
        if (!((MASK >> t) & 1u)) continue;
#pragma unroll
        for (int c = 0; c < 8; ++c) acc[t][c] = 0.f;
    }

    constexpr int KMAX = topbit(MASK);   // highest masked t; k in [0, KMAX)
    for (int k = 0; k < KMAX; ++k) {
        const float fxk = cum_flow[(k * 2 + 0) * HWc + pix];
        const float fyk = cum_flow[(k * 2 + 1) * HWc + pix];
        const unsigned short* __restrict__ bk = imgTb + (size_t)k * HWc * Cc;
        do_chunk16<LOOPM, 1, 7>(k, bk, half, sx1, sy1, fxk, fyk, wtab, acc);
        do_chunk16<LOOPM, 8, 15>(k, bk, half, sx1, sy1, fxk, fyk, wtab, acc);
    }

    // Epilogue: add exact fp32 identity sample (t==k, weight 1) and store.
#pragma unroll
    for (int t = 0; t < Lc; ++t) {
        if (!((MASK >> t) & 1u)) continue;
        const float* __restrict__ ip = img + ((size_t)t * Cc + 8 * half) * HWc + pix;
        float* __restrict__ op = out + ((size_t)t * Cc + 8 * half) * HWc + pix;
#pragma unroll
        for (int c = 0; c < 8; ++c)
            op[c * HWc] = acc[t][c] + ip[c * HWc];
    }
}

// ---------------------------------------------------------------------------
// Kernel 2: wave-level t-quartered HALF-layout accumulate (16B gathers).
// Block = 32 px x 2 ch-halves x 4 waves. Wave id (tid>>6) picks a t-quarter
// {15,8,5,2} {14,9,6,1} {13,10,4,3} {12,11,7,0} (30 (k,t)-pairs each,
// spread so every 8-range has <=2 active t -> bounded load buffers).
// vs round 4 (same dur as round 1 at 84us, per-wave issue rate HALVED as
// waves doubled -> shared per-CU VMEM/TA path saturated, not wave-starved):
//  - 16B uint4 gathers, 2 lanes/px: scatter wave-instrs 3840 -> 1920 per CU,
//    coordinate math per px 480 -> 240 computations;
//  - block plane-footprint = 32 px = exactly one 128B line -> full-line
//    identity reads and stores (round 4's 16px/64B partial lines showed as
//    WRITE 61MB ~ 2x output and FETCH 132MB);
//  - quarters share the block -> frames swept in k-lockstep, disjoint
//    t-plane writes, wave-uniform masks (no divergence).
// 1024 blocks = 4/CU x 4 waves = 16 waves/CU; band = b&7 -> XCD.
// ---------------------------------------------------------------------------
__global__ __launch_bounds__(256, 4) void gridsample_bf16_h16(
    const unsigned short* __restrict__ imgTb,  // (L, H, W, C) bf16
    const float* __restrict__ cum_flow,        // (L, 2, H, W)
    const float* __restrict__ mask,            // (L, L)
    const float* __restrict__ decay,           // (L, L)
    const float* __restrict__ img,             // (L, C, H, W) f32, identity
    float* __restrict__ out)                   // (L, C, H, W)
{
    __shared__ float wtab[Lc * Lc];
    const int tid = threadIdx.x;
    if (tid < Lc * Lc)
        wtab[tid] = mask[tid] * __expf(-DECAYc * decay[tid]);
    __syncthreads();

    const int half = tid & 1;            // channel half: 8*half .. 8*half+7
    const int px32 = (tid >> 1) & 31;    // pixel within block
    const int wv   = tid >> 6;           // wave id = t-quarter
    const int b    = blockIdx.x;         // 0..1023
    const int band = b & 7;              // XCD id under modulo dispatch
    const int sub  = b >> 3;             // 0..127 within band
    const int h = band * 16 + (sub >> 3);
    const int w = (sub & 7) * 32 + px32;
    const int pix = h * Wc + w;

    const float base_x = w * (2.0f / Wc) - 1.0f + 1.0f / Wc;
    const float base_y = h * (2.0f / Hc) - 1.0f + 1.0f / Hc;

    switch (wv) {
        case 0:  run_quarter<0x8124u>(imgTb, cum_flow, img, out, wtab, half, pix, base_x, base_y); break; // {15,8,5,2}
        case 1:  run_quarter<0x4242u>(imgTb, cum_flow, img, out, wtab, half, pix, base_x, base_y); break; // {14,9,6,1}
        case 2:  run_quarter<0x2418u>(imgTb, cum_flow, img, out, wtab, half, pix, base_x, base_y); break; // {13,10,4,3}
        default: run_quarter<0x1881u>(imgTb, cum_flow, img, out, wtab, half, pix, base_x, base_y); break; // {12,11,7,0}
    }
}

// ---------------------------------------------------------------------------
// Fallback (Round-1 kernel): used only if ws_size is too small.
// ---------------------------------------------------------------------------
__global__ __launch_bounds__(256) void gridsample_warp_acc(
    const float* __restrict__ img, const float* __restrict__ cum_flow,
    const float* __restrict__ mask, const float* __restrict__ decay,
    float* __restrict__ out)
{
    const int w = threadIdx.x, h = blockIdx.x, t = blockIdx.y;
    const int pix = h * Wc + w;
    const float base_x = w * (2.0f / Wc) - 1.0f + 1.0f / Wc;
    const float base_y = h * (2.0f / Hc) - 1.0f + 1.0f / Hc;
    const float fxt = cum_flow[(t * 2 + 0) * HWc + pix];
    const float fyt = cum_flow[(t * 2 + 1) * HWc + pix];
    float acc[Cc];
#pragma unroll
    for (int c = 0; c < Cc; ++c) acc[c] = 0.0f;
    for (int k = 0; k <= t; ++k) {
        const float wkt = mask[t * Lc + k] * __expf(-DECAYc * decay[t * Lc + k]);
        const float fxk = cum_flow[(k * 2 + 0) * HWc + pix];
        const float fyk = cum_flow[(k * 2 + 1) * HWc + pix];
        float gx = base_x + (fxt - fxk);
        const float gy = base_y + (fyt - fyk);
        float m = gx + 1.0f;
        m -= 2.0f * floorf(m * 0.5f);
        gx = m - 1.0f;
        const float ix = (gx + 1.0f) * (Wc * 0.5f) - 0.5f;
        const float iy = (gy + 1.0f) * (Hc * 0.5f) - 0.5f;
        const float x0f = floorf(ix), y0f = floorf(iy);
        const float wx = ix - x0f, wy = iy - y0f;
        const int x0 = (int)x0f, y0 = (int)y0f;
        const int x0r = x0 & (Wc - 1), x1r = (x0 + 1) & (Wc - 1);
        const int y0c = min(max(y0, 0), Hc - 1), y1c = min(max(y0 + 1, 0), Hc - 1);
        const float a00 = wkt * (1.0f - wx) * (1.0f - wy);
        const float a01 = wkt * (1.0f - wx) * wy;
        const float a10 = wkt * wx * (1.0f - wy);
        const float a11 = wkt * wx * wy;
        const int o00 = y0c * Wc + x0r, o01 = y1c * Wc + x0r;
        const int o10 = y0c * Wc + x1r, o11 = y1c * Wc + x1r;
        const float* __restrict__ ik = img + (size_t)k * Cc * HWc;
#pragma unroll
        for (int c = 0; c < Cc; ++c) {
            const float* __restrict__ p = ik + c * HWc;
            acc[c] += p[o00] * a00 + p[o01] * a01 + p[o10] * a10 + p[o11] * a11;
        }
    }
    float* __restrict__ op = out + (size_t)t * Cc * HWc + pix;
#pragma unroll
    for (int c = 0; c < Cc; ++c) op[c * HWc] = acc[c];
}

extern "C" void kernel_launch(void* const* d_in, const int* in_sizes, int n_in,
                              void* d_out, int out_size, void* d_ws, size_t ws_size,
                              hipStream_t stream) {
    const float* img      = (const float*)d_in[0];
    const float* cum_flow = (const float*)d_in[1];
    const float* mask     = (const float*)d_in[2];
    const float* decay    = (const float*)d_in[3];
    float* out = (float*)d_out;

    const size_t needed = (size_t)Lc * HWc * Cc * sizeof(unsigned short);  // 16 MB
    if (ws_size >= needed) {
        unsigned short* imgTb = (unsigned short*)d_ws;
        transpose_cvt_bf16<<<dim3(512), 256, 0, stream>>>(img, imgTb);
        gridsample_bf16_h16<<<dim3(1024), 256, 0, stream>>>(
            imgTb, cum_flow, mask, decay, img, out);
    } else {
        dim3 grid(Hc, Lc, 1);
        gridsample_warp_acc<<<grid, Wc, 0, stream>>>(img, cum_flow, mask, decay, out);
    }
}